// Round 12
// baseline (267.961 us; speedup 1.0000x reference)
//
#include <hip/hip_runtime.h>
#include <math.h>

typedef _Float16 f16x8 __attribute__((ext_vector_type(8)));
typedef float    f32x4 __attribute__((ext_vector_type(4)));
typedef float    f32x2 __attribute__((ext_vector_type(2)));
typedef _Float16 f16x2 __attribute__((ext_vector_type(2)));
typedef __fp16   fp16x2 __attribute__((ext_vector_type(2)));

#define B_TOT 2048
#define LSEQ  512
#define NS    8            // samples per block; 256 blocks -> all 256 CUs
#define LOG2E 1.44269504088896f
#define LN2   0.69314718055995f

#define MFMA16(A, B, C) __builtin_amdgcn_mfma_f32_16x16x32_f16((A), (B), (C), 0, 0, 0)

__device__ __forceinline__ unsigned int pkrtz(float a, float b) {
    fp16x2 p = __builtin_amdgcn_cvt_pkrtz(a, b);
    return __builtin_bit_cast(unsigned int, p);
}

__global__ __launch_bounds__(256, 1)
void lstm_v25_kernel(const int* __restrict__ s,
                     const float* __restrict__ W0, const float* __restrict__ b0,
                     const float* __restrict__ Wi, const float* __restrict__ Wh,
                     const float* __restrict__ bh, const float* __restrict__ Wa,
                     const float* __restrict__ ba, const float* __restrict__ Wp,
                     const float* __restrict__ bp, float* __restrict__ out)
{
    const int tid  = threadIdx.x;
    const int w    = tid >> 6;     // wave 0..3: feature block 16w..16w+15 (all 4 gates)
    const int lane = tid & 63;
    const int n    = lane & 15;    // MFMA column; samples duplicated: col n == col n+8
    const int q    = lane >> 4;
    const int ns   = n & 7;        // sample index
    const int hi   = n >> 3;       // row-half: lane n<8 -> acc rows {0,1}, n>=8 -> {2,3}
    const int b0s  = blockIdx.x * NS;

    // h layout: sample sN, chunk c (features 8c..8c+7) = 4 dwords at
    // 4*sN + 64*(c&1) + 128*(c>>1).  Each lane publishes ONE dword (2 features),
    // reads 2x ds_read_b128; cols n/n+8 read the same address (broadcast, free).
    __shared__ __align__(16) unsigned int HhD[2][512];  //  4 KB
    __shared__ unsigned short TOKB[LSEQ + 2];           //  1 KB
    __shared__ unsigned char  SRAW[NS][LSEQ];           //  4 KB
    __shared__ _Float16 DBUF[LSEQ][NS];                 //  8 KB
    __shared__ float PART[32][NS];                      //  1 KB

    // ---- stage tokens (coalesced in t) ----
    for (int i = tid; i < NS * LSEQ; i += 256)
        SRAW[i >> 9][i & 511] = (unsigned char)s[(b0s + (i >> 9)) * LSEQ + (i & 511)];
    __syncthreads();
    for (int u = tid; u <= LSEQ; u += 256) {
        unsigned int mask = 0;
        if (u >= 1) {
            #pragma unroll
            for (int m = 0; m < NS; ++m)
                mask |= ((unsigned int)SRAW[m][u - 1]) << m;
        }
        TOKB[u] = (unsigned short)mask;
    }

    // ---- A-frags: scaled Wh^T (row m = n, full 16 rows) ----
    f16x8 awh[4][2];
    #pragma unroll
    for (int g = 0; g < 4; ++g) {
        const float sc  = (g == 2) ? (2.0f * LOG2E) : (-LOG2E);
        const int   col = 64 * g + 16 * w + n;
        #pragma unroll
        for (int c = 0; c < 2; ++c)
            #pragma unroll
            for (int j = 0; j < 8; ++j)
                awh[g][c][j] = (_Float16)(Wh[(32 * c + 8 * q + j) * 256 + col] * sc);
    }

    // ---- d-GEMM A-frag: row 0 = Wa[:,1]-Wa[:,0] ----
    f16x8 awd[2];
    #pragma unroll
    for (int c = 0; c < 2; ++c)
        #pragma unroll
        for (int j = 0; j < 8; ++j) {
            int k = 32 * c + 8 * q + j;
            awd[c][j] = (_Float16)((n == 0) ? (Wa[2 * k + 1] - Wa[2 * k]) : 0.0f);
        }
    const float dba = ba[1] - ba[0];

    // ---- p0 (scaled, full quad: loop-invariant MFMA C) and the lane's OWN
    // 2-row slice of dp (token correction applied post-extraction) ----
    f32x4 p0q[4];
    f32x2 dpi, dpf, dpg, dpo;
    {
        float a0[4][4], a1[4][4];
        #pragma unroll
        for (int g = 0; g < 4; ++g)
            #pragma unroll
            for (int r = 0; r < 4; ++r) {
                float bb = bh[64 * g + 16 * w + 4 * q + r];
                a0[g][r] = bb; a1[g][r] = bb;
            }
        for (int f = 0; f < 64; ++f) {
            float wb0 = W0[f]      + b0[f];
            float wb1 = W0[64 + f] + b0[f];
            #pragma unroll
            for (int g = 0; g < 4; ++g) {
                const float4 wi4 = *(const float4*)&Wi[f * 256 + 64 * g + 16 * w + 4 * q];
                #pragma unroll
                for (int r = 0; r < 4; ++r) {
                    float wi = (&wi4.x)[r];
                    a0[g][r] = fmaf(wb0, wi, a0[g][r]);
                    a1[g][r] = fmaf(wb1, wi, a1[g][r]);
                }
            }
        }
        f32x4 dpq[4];
        #pragma unroll
        for (int g = 0; g < 4; ++g) {
            const float sc = (g == 2) ? (2.0f * LOG2E) : (-LOG2E);
            #pragma unroll
            for (int r = 0; r < 4; ++r) {
                p0q[g][r] = a0[g][r] * sc;
                dpq[g][r] = (a1[g][r] - a0[g][r]) * sc;
            }
        }
        const bool hb2 = (hi != 0);
        dpi = (f32x2){ hb2 ? dpq[0][2] : dpq[0][0], hb2 ? dpq[0][3] : dpq[0][1] };
        dpf = (f32x2){ hb2 ? dpq[1][2] : dpq[1][0], hb2 ? dpq[1][3] : dpq[1][1] };
        dpg = (f32x2){ hb2 ? dpq[2][2] : dpq[2][0], hb2 ? dpq[2][3] : dpq[2][1] };
        dpo = (f32x2){ hb2 ? dpq[3][2] : dpq[3][0], hb2 ? dpq[3][3] : dpq[3][1] };
    }

    __syncthreads();   // TOKB ready

    // ---- loop-invariant LDS dword addresses ----
    const int wAddr = 4 * ns + 64 * (q >> 1) + 128 * w + 2 * (q & 1) + hi;
    const int rAddr = 4 * ns + 64 * (q & 1) + 128 * (q >> 1);

    // ---- state: 2 cells per lane, packed pair ----
    f32x2 h2 = {0.f, 0.f}, c2 = {0.f, 0.f};
    const f32x2 one2 = {1.f, 1.f};
    float dpend = 0.0f;      // wave 0's deferred d-result (written one step late)

    #pragma unroll 4
    for (int v = 0; v <= LSEQ; ++v) {
        const int p = v & 1;
        unsigned int* __restrict__ hb = &HhD[p][0];

        // publish h_{v-1} (head of serial chain); token read issued pre-barrier
        // so its LDS latency hides under the barrier wait (TOKB is read-only)
        hb[wAddr] = pkrtz(h2[0], h2[1]);
        const unsigned int tokm = (unsigned int)TOKB[v];   // s_pad[v] mask
        __syncthreads();

        // B-frags: two ds_read_b128 (cols n / n+8 broadcast same sample)
        uint4 r0 = *(const uint4*)&hb[rAddr];
        uint4 r1 = *(const uint4*)&hb[rAddr + 256];
        const f16x8 bf0 = __builtin_bit_cast(f16x8, r0);
        const f16x8 bf1 = __builtin_bit_cast(f16x8, r1);

        // flush wave0's deferred d-result for t = v-2 (after the reads: DS is
        // in-order per wave, so this b16 write doesn't delay the b128 data)
        if (v >= 2 && w == 0) {
            if (lane < 8) DBUF[v - 2][n] = (_Float16)dpend;
        }

        const float sel = (float)((tokm >> ns) & 1u);
        const f32x2 sel2 = {sel, sel};
        const bool hb2 = (hi != 0);

        // ---- gates GEMM, per-gate pipelined (C = loop-invariant p0q);
        // extract+correct+exp2 of gate g runs under gate g+2's MFMA issue ----
        f32x4 acc0, acc1, acc2, acc3;
        acc0 = MFMA16(awh[0][0], bf0, p0q[0]);
        acc0 = MFMA16(awh[0][1], bf1, acc0);
        acc1 = MFMA16(awh[1][0], bf0, p0q[1]);
        acc1 = MFMA16(awh[1][1], bf1, acc1);

        f32x2 gi = { hb2 ? acc0[2] : acc0[0], hb2 ? acc0[3] : acc0[1] };
        gi = sel2 * dpi + gi;
        f32x2 ei = { __builtin_amdgcn_exp2f(gi[0]), __builtin_amdgcn_exp2f(gi[1]) };

        acc2 = MFMA16(awh[2][0], bf0, p0q[2]);
        acc2 = MFMA16(awh[2][1], bf1, acc2);

        f32x2 gf = { hb2 ? acc1[2] : acc1[0], hb2 ? acc1[3] : acc1[1] };
        gf = sel2 * dpf + gf;
        f32x2 ef = { __builtin_amdgcn_exp2f(gf[0]), __builtin_amdgcn_exp2f(gf[1]) };

        acc3 = MFMA16(awh[3][0], bf0, p0q[3]);
        acc3 = MFMA16(awh[3][1], bf1, acc3);

        f32x2 gg = { hb2 ? acc2[2] : acc2[0], hb2 ? acc2[3] : acc2[1] };
        gg = sel2 * dpg + gg;
        f32x2 eg = { __builtin_amdgcn_exp2f(gg[0]), __builtin_amdgcn_exp2f(gg[1]) };

        // d-GEMM last (off the gate->extract chain): all waves compute
        // (identical streams, no straggler); only wave 0's result consumed.
        if (v >= 1) {
            f32x4 da = (f32x4){dba, dba, dba, dba};
            da = MFMA16(awd[0], bf0, da);
            da = MFMA16(awd[1], bf1, da);
            dpend = da[0];
        }

        f32x2 go = { hb2 ? acc3[2] : acc3[0], hb2 ? acc3[3] : acc3[1] };
        go = sel2 * dpo + go;
        f32x2 eo = { __builtin_amdgcn_exp2f(go[0]), __builtin_amdgcn_exp2f(go[1]) };

        // ---- act merge (identical algebra to v22/v24) ----
        f32x2 P  = (one2 + ei) * (eg + one2);
        f32x2 F  = one2 + ef;
        f32x2 PF = P * F;
        f32x2 R2 = { __builtin_amdgcn_rcpf(PF[0]), __builtin_amdgcn_rcpf(PF[1]) };
        f32x2 cn = (c2 * P) * R2 + ((eg - one2) * F) * R2;
        c2 = cn;
        f32x2 ar = cn * (f32x2){2.0f * LOG2E, 2.0f * LOG2E};
        ar = (f32x2){ fminf(ar[0], 60.f), fminf(ar[1], 60.f) };
        f32x2 ec = { __builtin_amdgcn_exp2f(ar[0]), __builtin_amdgcn_exp2f(ar[1]) };
        f32x2 dn = (one2 + eo) * (ec + one2);
        f32x2 Ro = { __builtin_amdgcn_rcpf(dn[0]), __builtin_amdgcn_rcpf(dn[1]) };
        h2 = (ec - one2) * Ro;
    }

    // ---- tail: flush wave0's last d (t=511), publish h_512 into buffer 1 ----
    if (w == 0 && lane < 8) DBUF[511][n] = (_Float16)dpend;
    HhD[1][wAddr] = pkrtz(h2[0], h2[1]);
    __syncthreads();

    // ---- amp post-pass: 8 samples x 512 t, 16 t per thread ----
    {
        const int nn = tid & 7;
        const int cp = tid >> 3;             // 0..31
        float a = 0.0f;
        #pragma unroll 4
        for (int k = 0; k < 16; ++k) {
            int t = cp * 16 + k;
            float d = (float)DBUF[t][nn];
            float x = SRAW[nn][t] ? -d : d;
            float e = __builtin_amdgcn_exp2f(-fabsf(x) * LOG2E);
            a += fmaxf(x, 0.0f) + __builtin_amdgcn_logf(1.0f + e) * LN2;
        }
        PART[cp][nn] = a;
    }
    __syncthreads();

    if (tid < 8) {
        float ssum = 0.0f;
        #pragma unroll
        for (int c = 0; c < 32; ++c) ssum += PART[c][tid];
        out[b0s + tid] = -0.5f * ssum;              // planar real
    }

    // ---- phase: wave 0; lane (n,q) covers features 16q..16q+15 of sample ns
    if (w == 0) {
        float ph = 0.0f;
        #pragma unroll
        for (int d = 0; d < 4; ++d) {
            unsigned int ua = HhD[1][4 * ns + 128 * q + d];
            unsigned int ub = HhD[1][4 * ns + 64 + 128 * q + d];
            f16x2 ha = __builtin_bit_cast(f16x2, ua);
            f16x2 hc = __builtin_bit_cast(f16x2, ub);
            ph = fmaf((float)ha[0], Wp[16 * q + 2 * d],
                 fmaf((float)ha[1], Wp[16 * q + 2 * d + 1], ph));
            ph = fmaf((float)hc[0], Wp[16 * q + 8 + 2 * d],
                 fmaf((float)hc[1], Wp[16 * q + 8 + 2 * d + 1], ph));
        }
        ph += __shfl_xor(ph, 16, 64);
        ph += __shfl_xor(ph, 32, 64);
        if (q == 0 && n < 8) out[B_TOT + b0s + n] = ph + bp[0];   // planar imag
    }
}

extern "C" void kernel_launch(void* const* d_in, const int* in_sizes, int n_in,
                              void* d_out, int out_size, void* d_ws, size_t ws_size,
                              hipStream_t stream) {
    const int*   s  = (const int*)  d_in[0];
    const float* W0 = (const float*)d_in[1];
    const float* b0 = (const float*)d_in[2];
    const float* Wi = (const float*)d_in[3];
    const float* Wh = (const float*)d_in[4];
    const float* bh = (const float*)d_in[5];
    const float* Wa = (const float*)d_in[6];
    const float* ba = (const float*)d_in[7];
    const float* Wp = (const float*)d_in[8];
    const float* bp = (const float*)d_in[9];
    float* out = (float*)d_out;

    dim3 grid(B_TOT / NS);   // 256 WGs x 4 waves (v16/v22/v24 topology)
    dim3 block(256);
    lstm_v25_kernel<<<grid, block, 0, stream>>>(s, W0, b0, Wi, Wh, bh,
                                                Wa, ba, Wp, bp, out);
}

// Round 13
// 264.069 us; speedup vs baseline: 1.0147x; 1.0147x over previous
//
#include <hip/hip_runtime.h>
#include <math.h>

typedef _Float16 f16x8 __attribute__((ext_vector_type(8)));
typedef float    f32x4 __attribute__((ext_vector_type(4)));
typedef float    f32x2 __attribute__((ext_vector_type(2)));
typedef _Float16 f16x2 __attribute__((ext_vector_type(2)));
typedef __fp16   fp16x2 __attribute__((ext_vector_type(2)));

#define B_TOT 2048
#define LSEQ  512
#define NS    8            // samples per block; 256 blocks -> all 256 CUs
#define LOG2E 1.44269504088896f
#define LN2   0.69314718055995f

#define MFMA16(A, B, C) __builtin_amdgcn_mfma_f32_16x16x32_f16((A), (B), (C), 0, 0, 0)

__device__ __forceinline__ unsigned int pkrtz(float a, float b) {
    fp16x2 p = __builtin_amdgcn_cvt_pkrtz(a, b);
    return __builtin_bit_cast(unsigned int, p);
}

// v26 = exact revert to v24 (session champion, 218.5 us counter-level).
// v25's lesson baked in as comments: the token C-correction MUST ride the MFMA
// C operand (built in the previous step's trans shadow, zero chain cost), and
// the C-init pk-FMAs are shadow-resident latency fillers -- do not remove.
__global__ __launch_bounds__(256, 1)
void lstm_v26_kernel(const int* __restrict__ s,
                     const float* __restrict__ W0, const float* __restrict__ b0,
                     const float* __restrict__ Wi, const float* __restrict__ Wh,
                     const float* __restrict__ bh, const float* __restrict__ Wa,
                     const float* __restrict__ ba, const float* __restrict__ Wp,
                     const float* __restrict__ bp, float* __restrict__ out)
{
    const int tid  = threadIdx.x;
    const int w    = tid >> 6;     // wave 0..3: feature block 16w..16w+15 (all 4 gates)
    const int lane = tid & 63;
    const int n    = lane & 15;    // MFMA column; samples duplicated: col n == col n+8
    const int q    = lane >> 4;
    const int ns   = n & 7;        // sample index
    const int hi   = n >> 3;       // row-half: lane n<8 -> acc rows {0,1}, n>=8 -> {2,3}
    const int b0s  = blockIdx.x * NS;

    // h layout: sample sN, chunk c (features 8c..8c+7) = 4 dwords at
    // 4*sN + 64*(c&1) + 128*(c>>1).  Each lane publishes ONE dword (2 features),
    // reads 2x ds_read_b128; cols n/n+8 read the same address (broadcast, free).
    __shared__ __align__(16) unsigned int HhD[2][512];  //  4 KB
    __shared__ unsigned short TOKB[LSEQ + 2];           //  1 KB
    __shared__ unsigned char  SRAW[NS][LSEQ];           //  4 KB
    __shared__ _Float16 DBUF[LSEQ][NS];                 //  8 KB
    __shared__ float PART[32][NS];                      //  1 KB

    // ---- stage tokens (coalesced in t) ----
    for (int i = tid; i < NS * LSEQ; i += 256)
        SRAW[i >> 9][i & 511] = (unsigned char)s[(b0s + (i >> 9)) * LSEQ + (i & 511)];
    __syncthreads();
    for (int u = tid; u <= LSEQ; u += 256) {
        unsigned int mask = 0;
        if (u >= 1) {
            #pragma unroll
            for (int m = 0; m < NS; ++m)
                mask |= ((unsigned int)SRAW[m][u - 1]) << m;
        }
        TOKB[u] = (unsigned short)mask;
    }

    // ---- A-frags: scaled Wh^T (row m = n, full 16 rows) ----
    f16x8 awh[4][2];
    #pragma unroll
    for (int g = 0; g < 4; ++g) {
        const float sc  = (g == 2) ? (2.0f * LOG2E) : (-LOG2E);
        const int   col = 64 * g + 16 * w + n;
        #pragma unroll
        for (int c = 0; c < 2; ++c)
            #pragma unroll
            for (int j = 0; j < 8; ++j)
                awh[g][c][j] = (_Float16)(Wh[(32 * c + 8 * q + j) * 256 + col] * sc);
    }

    // ---- d-GEMM A-frag: row 0 = Wa[:,1]-Wa[:,0] ----
    f16x8 awd[2];
    #pragma unroll
    for (int c = 0; c < 2; ++c)
        #pragma unroll
        for (int j = 0; j < 8; ++j) {
            int k = 32 * c + 8 * q + j;
            awd[c][j] = (_Float16)((n == 0) ? (Wa[2 * k + 1] - Wa[2 * k]) : 0.0f);
        }
    const float dba = ba[1] - ba[0];

    // ---- p0/dp (scaled), full 4 rows per lane (MFMA C operand) ----
    f32x4 p0q[4], dpq[4];
    {
        float a0[4][4], a1[4][4];
        #pragma unroll
        for (int g = 0; g < 4; ++g)
            #pragma unroll
            for (int r = 0; r < 4; ++r) {
                float bb = bh[64 * g + 16 * w + 4 * q + r];
                a0[g][r] = bb; a1[g][r] = bb;
            }
        for (int f = 0; f < 64; ++f) {
            float wb0 = W0[f]      + b0[f];
            float wb1 = W0[64 + f] + b0[f];
            #pragma unroll
            for (int g = 0; g < 4; ++g) {
                const float4 wi4 = *(const float4*)&Wi[f * 256 + 64 * g + 16 * w + 4 * q];
                #pragma unroll
                for (int r = 0; r < 4; ++r) {
                    float wi = (&wi4.x)[r];
                    a0[g][r] = fmaf(wb0, wi, a0[g][r]);
                    a1[g][r] = fmaf(wb1, wi, a1[g][r]);
                }
            }
        }
        #pragma unroll
        for (int g = 0; g < 4; ++g) {
            const float sc = (g == 2) ? (2.0f * LOG2E) : (-LOG2E);
            #pragma unroll
            for (int r = 0; r < 4; ++r) {
                p0q[g][r] = a0[g][r] * sc;
                dpq[g][r] = (a1[g][r] - a0[g][r]) * sc;
            }
        }
    }

    __syncthreads();   // TOKB ready

    // ---- loop-invariant LDS dword addresses ----
    const int wAddr = 4 * ns + 64 * (q >> 1) + 128 * w + 2 * (q & 1) + hi;
    const int rAddr = 4 * ns + 64 * (q & 1) + 128 * (q >> 1);

    // ---- state: 2 cells per lane, packed pair ----
    f32x2 h2 = {0.f, 0.f}, c2 = {0.f, 0.f};
    f32x4 ci[4];
    #pragma unroll
    for (int g = 0; g < 4; ++g) ci[g] = p0q[g];

    const f32x2 one2 = {1.f, 1.f};
    float dpend = 0.0f;      // wave 0's deferred d-result (written one step late)

    #pragma unroll 4
    for (int v = 0; v <= LSEQ; ++v) {
        const int p = v & 1;
        unsigned int* __restrict__ hb = &HhD[p][0];

        // publish h_{v-1}: one ds_write_b32 (head of the serial chain -> first)
        hb[wAddr] = pkrtz(h2[0], h2[1]);
        __syncthreads();

        // B-frags: two ds_read_b128 (cols n / n+8 broadcast same sample)
        uint4 r0 = *(const uint4*)&hb[rAddr];
        uint4 r1 = *(const uint4*)&hb[rAddr + 256];
        const f16x8 bf0 = __builtin_bit_cast(f16x8, r0);
        const f16x8 bf1 = __builtin_bit_cast(f16x8, r1);

        // flush wave0's deferred d-result for t = v-2 (after the reads: DS is
        // in-order per wave, so this b16 write doesn't delay the b128 data)
        if (v >= 2 && w == 0) {
            if (lane < 8) DBUF[v - 2][n] = (_Float16)dpend;
        }

        const unsigned int tokm_next = (v < LSEQ) ? (unsigned int)TOKB[v + 1] : 0u;
        const bool hb2 = (hi != 0);

        // ---- gates GEMM, per-gate pipelined: extract+exp2 of gate g runs
        // under the MFMA issue of gate g+2 (trans overlap MFMA shadow) ----
        f32x4 acc0 = ci[0], acc1 = ci[1], acc2 = ci[2], acc3 = ci[3];
        acc0 = MFMA16(awh[0][0], bf0, acc0);
        acc0 = MFMA16(awh[0][1], bf1, acc0);
        acc1 = MFMA16(awh[1][0], bf0, acc1);
        acc1 = MFMA16(awh[1][1], bf1, acc1);

        f32x2 gi = { hb2 ? acc0[2] : acc0[0], hb2 ? acc0[3] : acc0[1] };
        f32x2 ei = { __builtin_amdgcn_exp2f(gi[0]), __builtin_amdgcn_exp2f(gi[1]) };

        acc2 = MFMA16(awh[2][0], bf0, acc2);
        acc2 = MFMA16(awh[2][1], bf1, acc2);

        f32x2 gf = { hb2 ? acc1[2] : acc1[0], hb2 ? acc1[3] : acc1[1] };
        f32x2 ef = { __builtin_amdgcn_exp2f(gf[0]), __builtin_amdgcn_exp2f(gf[1]) };

        acc3 = MFMA16(awh[3][0], bf0, acc3);
        acc3 = MFMA16(awh[3][1], bf1, acc3);

        f32x2 gg = { hb2 ? acc2[2] : acc2[0], hb2 ? acc2[3] : acc2[1] };
        f32x2 eg = { __builtin_amdgcn_exp2f(gg[0]), __builtin_amdgcn_exp2f(gg[1]) };

        // d-GEMM last (off the gate->extract chain): all waves compute
        // (identical streams, no straggler); only wave 0's result consumed.
        if (v >= 1) {
            f32x4 da = (f32x4){dba, dba, dba, dba};
            da = MFMA16(awd[0], bf0, da);
            da = MFMA16(awd[1], bf1, da);
            dpend = da[0];
        }

        f32x2 go = { hb2 ? acc3[2] : acc3[0], hb2 ? acc3[3] : acc3[1] };
        f32x2 eo = { __builtin_amdgcn_exp2f(go[0]), __builtin_amdgcn_exp2f(go[1]) };

        // C-init for next iter: token correction rides the MFMA C operand,
        // built HERE in the trans shadow (v25 lesson: moving it onto the
        // extract->exp2 chain costs ~300 cyc/step). Shadow-resident; keep.
        const float sel = (float)((tokm_next >> ns) & 1u);
        const f32x4 sel4 = {sel, sel, sel, sel};
        #pragma unroll
        for (int g = 0; g < 4; ++g)
            ci[g] = dpq[g] * sel4 + p0q[g];

        // ---- act merge (algebraic minimum: 5 exp2 + 2 rcp per cell) ----
        f32x2 P  = (one2 + ei) * (eg + one2);
        f32x2 F  = one2 + ef;
        f32x2 PF = P * F;
        f32x2 R2 = { __builtin_amdgcn_rcpf(PF[0]), __builtin_amdgcn_rcpf(PF[1]) };
        f32x2 cn = (c2 * P) * R2 + ((eg - one2) * F) * R2;
        c2 = cn;
        f32x2 ar = cn * (f32x2){2.0f * LOG2E, 2.0f * LOG2E};
        ar = (f32x2){ fminf(ar[0], 60.f), fminf(ar[1], 60.f) };
        f32x2 ec = { __builtin_amdgcn_exp2f(ar[0]), __builtin_amdgcn_exp2f(ar[1]) };
        f32x2 dn = (one2 + eo) * (ec + one2);
        f32x2 Ro = { __builtin_amdgcn_rcpf(dn[0]), __builtin_amdgcn_rcpf(dn[1]) };
        h2 = (ec - one2) * Ro;
    }

    // ---- tail: flush wave0's last d (t=511), publish h_512 into buffer 1 ----
    if (w == 0 && lane < 8) DBUF[511][n] = (_Float16)dpend;
    HhD[1][wAddr] = pkrtz(h2[0], h2[1]);
    __syncthreads();

    // ---- amp post-pass: 8 samples x 512 t, 16 t per thread ----
    {
        const int nn = tid & 7;
        const int cp = tid >> 3;             // 0..31
        float a = 0.0f;
        #pragma unroll 4
        for (int k = 0; k < 16; ++k) {
            int t = cp * 16 + k;
            float d = (float)DBUF[t][nn];
            float x = SRAW[nn][t] ? -d : d;
            float e = __builtin_amdgcn_exp2f(-fabsf(x) * LOG2E);
            a += fmaxf(x, 0.0f) + __builtin_amdgcn_logf(1.0f + e) * LN2;
        }
        PART[cp][nn] = a;
    }
    __syncthreads();

    if (tid < 8) {
        float ssum = 0.0f;
        #pragma unroll
        for (int c = 0; c < 32; ++c) ssum += PART[c][tid];
        out[b0s + tid] = -0.5f * ssum;              // planar real
    }

    // ---- phase: wave 0; lane (n,q) covers features 16q..16q+15 of sample ns
    if (w == 0) {
        float ph = 0.0f;
        #pragma unroll
        for (int d = 0; d < 4; ++d) {
            unsigned int ua = HhD[1][4 * ns + 128 * q + d];
            unsigned int ub = HhD[1][4 * ns + 64 + 128 * q + d];
            f16x2 ha = __builtin_bit_cast(f16x2, ua);
            f16x2 hc = __builtin_bit_cast(f16x2, ub);
            ph = fmaf((float)ha[0], Wp[16 * q + 2 * d],
                 fmaf((float)ha[1], Wp[16 * q + 2 * d + 1], ph));
            ph = fmaf((float)hc[0], Wp[16 * q + 8 + 2 * d],
                 fmaf((float)hc[1], Wp[16 * q + 8 + 2 * d + 1], ph));
        }
        ph += __shfl_xor(ph, 16, 64);
        ph += __shfl_xor(ph, 32, 64);
        if (q == 0 && n < 8) out[B_TOT + b0s + n] = ph + bp[0];   // planar imag
    }
}

extern "C" void kernel_launch(void* const* d_in, const int* in_sizes, int n_in,
                              void* d_out, int out_size, void* d_ws, size_t ws_size,
                              hipStream_t stream) {
    const int*   s  = (const int*)  d_in[0];
    const float* W0 = (const float*)d_in[1];
    const float* b0 = (const float*)d_in[2];
    const float* Wi = (const float*)d_in[3];
    const float* Wh = (const float*)d_in[4];
    const float* bh = (const float*)d_in[5];
    const float* Wa = (const float*)d_in[6];
    const float* ba = (const float*)d_in[7];
    const float* Wp = (const float*)d_in[8];
    const float* bp = (const float*)d_in[9];
    float* out = (float*)d_out;

    dim3 grid(B_TOT / NS);   // 256 WGs x 4 waves (v16/v22/v24 topology)
    dim3 block(256);
    lstm_v26_kernel<<<grid, block, 0, stream>>>(s, W0, b0, Wi, Wh, bh,
                                                Wa, ba, Wp, bp, out);
}